// Round 1
// baseline (142.381 us; speedup 1.0000x reference)
//
#include <hip/hip_runtime.h>

typedef __attribute__((ext_vector_type(8))) short short8;
typedef __attribute__((ext_vector_type(4))) short short4v;
typedef __attribute__((ext_vector_type(4))) float f32x4;

#define B_ROWS 4096
#define IN_STRIDE 8384
#define OUT_STRIDE 131

static __device__ __forceinline__ short f2bf(float f) {
  unsigned u = __float_as_uint(f);
  u = u + 0x7FFFu + ((u >> 16) & 1u);   // RNE
  return (short)(u >> 16);
}
static __device__ __forceinline__ float bf2f(short s) {
  return __uint_as_float(((unsigned)(unsigned short)s) << 16);
}
static __device__ __forceinline__ float fast_tanh(float x) {
  float e = __builtin_amdgcn_exp2f(x * 2.8853900817779268f);  // e^(2x)
  return 1.0f - 2.0f * __builtin_amdgcn_rcpf(e + 1.0f);
}

// ---------------- prep: fold weights, bf16 casts, transposes ----------------
__global__ __launch_bounds__(256) void prep_kernel(
    const float* __restrict__ W_emb, const float* __restrict__ b_emb,
    const float* __restrict__ Uq, const float* __restrict__ Ur,
    const float* __restrict__ W1p, const float* __restrict__ W1v,
    const float* __restrict__ W2p, const float* __restrict__ W2v,
    const float* __restrict__ b1p, const float* __restrict__ b1v,
    const float* __restrict__ b2p, const float* __restrict__ b2v,
    short* __restrict__ WembUq, short* __restrict__ WembUrT,
    short* __restrict__ Wemb16, float* __restrict__ bUq, float* __restrict__ bUr,
    float* __restrict__ b1cat, float* __restrict__ b2cat,
    short* __restrict__ W1T, short* __restrict__ W2T)
{
  const int blk = blockIdx.x, t = threadIdx.x;
  if (blk < 128) {
    const int d = blk & 63;
    const float* U = (blk < 64) ? Uq : Ur;
    float acc = 0.f;
    for (int k = 0; k < 256; ++k) acc += W_emb[d * 256 + k] * U[k * 256 + t];
    if (blk < 64) WembUq[d * 256 + t] = f2bf(acc);
    else          WembUrT[t * 64 + d] = f2bf(acc);   // [n][k] transposed
  } else if (blk == 128) {
    float aq = 0.f, ar = 0.f;
    for (int k = 0; k < 256; ++k) {
      float b = b_emb[k];
      aq += b * Uq[k * 256 + t];
      ar += b * Ur[k * 256 + t];
    }
    bUq[t] = aq; bUr[t] = ar;
  } else if (blk == 129) {
    b1cat[t] = b1p[t]; b1cat[256 + t] = b1v[t];
    b2cat[t] = b2p[t]; b2cat[256 + t] = b2v[t];
    for (int i = 0; i < 64; ++i) Wemb16[i * 256 + t] = f2bf(W_emb[i * 256 + t]);
  } else if (blk < 770) {
    const int e = (blk - 130) * 256 + t;        // [0, 163840)
    const int n = e / 320, k = e - n * 320;     // W1T[n][k], n<512, k<320
    const float v = (n < 256) ? W1p[k * 256 + n] : W1v[k * 256 + (n - 256)];
    W1T[e] = f2bf(v);
  } else {
    const int e = (blk - 770) * 256 + t;        // [0, 131072)
    const int n = e >> 8, k = e & 255;          // W2T[n][k], n<512, k<256
    const float v = (n < 256) ? W2p[k * 256 + n] : W2v[k * 256 + (n - 256)];
    W2T[e] = f2bf(v);
  }
}

// ---------------- fused attention: 1 wave = 1 batch row ----------------
__global__ __launch_bounds__(256) void attn_kernel(
    const float* __restrict__ in, const short* __restrict__ BT,      // W_embUr^T [256][64]
    const short* __restrict__ WembUq, const short* __restrict__ Wemb16,
    const float* __restrict__ bUq, const float* __restrict__ bUr,
    const float* __restrict__ Ua, const float* __restrict__ b_emb,
    float* __restrict__ out, short* __restrict__ state)
{
  __shared__ short Blds[256 * 64];      // swizzled 16B chunks: chunk c of row n at c^(n&7)
  __shared__ float ua_lds[256];
  __shared__ float mask_lds[4][128];
  __shared__ float attn_lds[4][128];
  __shared__ float osum_lds[4][64];
  __shared__ float qU_lds[4][256];
  __shared__ float obar_lds[4][64];
  __shared__ float logit_lds[4][128];

  const int t = threadIdx.x, w = t >> 6, l = t & 63;
  const int q = l >> 4, r16 = l & 15;

  // block-cooperative: stage W_embUr^T into LDS (swizzled), Ua into LDS
  {
    const int4* src = (const int4*)BT;
    for (int it = 0; it < 8; ++it) {
      int cl = it * 256 + t;                 // chunk linear [0,2048)
      int n = cl >> 3, c = cl & 7;
      int4 v = src[cl];
      *(int4*)&Blds[n * 64 + ((c ^ (n & 7)) << 3)] = v;
    }
    ua_lds[t] = Ua[t];
  }
  __syncthreads();

  const int row = blockIdx.x * 4 + w;
  const float* __restrict__ xrow = in + (size_t)row * IN_STRIDE;
  const float* __restrict__ others = xrow + 64;
  const float* __restrict__ maskp = xrow + 8256;

  // phase A: mask -> LDS, S = sum(mask)
  float m0 = maskp[l], m1 = maskp[64 + l];
  mask_lds[w][l] = m0; mask_lds[w][64 + l] = m1;
  float S = m0 + m1;
#pragma unroll
  for (int d = 1; d < 64; d <<= 1) S += __shfl_xor(S, d);

  // phase B: stage masked others as bf16 A-fragments in registers + o_sum partials
  short8 afrag[8][2];
  float osA[8], osB[8];
#pragma unroll
  for (int j = 0; j < 8; ++j) { osA[j] = 0.f; osB[j] = 0.f; }
#pragma unroll
  for (int mt = 0; mt < 8; ++mt) {
    const int gr = mt * 16 + r16;
    const float mk = mask_lds[w][gr];
    const float4* p = (const float4*)(others + gr * 64 + q * 8);
    float4 a0 = p[0], a1 = p[1], c0 = p[8], c1 = p[9];
    float fa[8] = {a0.x, a0.y, a0.z, a0.w, a1.x, a1.y, a1.z, a1.w};
    float fb[8] = {c0.x, c0.y, c0.z, c0.w, c1.x, c1.y, c1.z, c1.w};
    short8 s0, s1;
#pragma unroll
    for (int j = 0; j < 8; ++j) {
      float va = fa[j] * mk, vb = fb[j] * mk;
      osA[j] += va; osB[j] += vb;
      s0[j] = f2bf(va); s1[j] = f2bf(vb);
    }
    afrag[mt][0] = s0; afrag[mt][1] = s1;
  }
  // reduce o_sum over the 16 lanes of each quarter (they cover different rows)
#pragma unroll
  for (int d = 1; d < 16; d <<= 1) {
#pragma unroll
    for (int j = 0; j < 8; ++j) {
      osA[j] += __shfl_xor(osA[j], d);
      osB[j] += __shfl_xor(osB[j], d);
    }
  }
  if (r16 == 0) {
#pragma unroll
    for (int j = 0; j < 8; ++j) {
      osum_lds[w][q * 8 + j] = osA[j];
      osum_lds[w][q * 8 + 32 + j] = osB[j];
    }
  }

  // phase C: qU[j] = (o_sum @ WembUq + S*bUq)/ (S+1e-5) + bUr   (bUr folded in)
  const float rS = __builtin_amdgcn_rcpf(S + 1e-5f);
  {
    float q0 = 0.f, q1 = 0.f, q2 = 0.f, q3 = 0.f;
    for (int d = 0; d < 64; ++d) {
      float os = osum_lds[w][d];
      short4v wv = *(const short4v*)&WembUq[d * 256 + l * 4];
      q0 += os * bf2f(wv[0]); q1 += os * bf2f(wv[1]);
      q2 += os * bf2f(wv[2]); q3 += os * bf2f(wv[3]);
    }
    const int j0 = l * 4;
    qU_lds[w][j0 + 0] = (q0 + S * bUq[j0 + 0]) * rS + bUr[j0 + 0];
    qU_lds[w][j0 + 1] = (q1 + S * bUq[j0 + 1]) * rS + bUr[j0 + 1];
    qU_lds[w][j0 + 2] = (q2 + S * bUq[j0 + 2]) * rS + bUr[j0 + 2];
    qU_lds[w][j0 + 3] = (q3 + S * bUq[j0 + 3]) * rS + bUr[j0 + 3];
  }

  // phase D: R = maskedOthers @ W_embUr (MFMA), fused tanh + Ua-dot into logits
  const f32x4 fzero = {0.f, 0.f, 0.f, 0.f};
  f32x4 lp[8];
#pragma unroll
  for (int mt = 0; mt < 8; ++mt) lp[mt] = fzero;

  for (int nt = 0; nt < 16; ++nt) {
    const int col = nt * 16 + r16;
    const float qv = qU_lds[w][col];
    const float uav = ua_lds[col];
    const int sw = col & 7;
    const short8 bf0 = *(const short8*)&Blds[col * 64 + (((q) ^ sw) << 3)];
    const short8 bf1 = *(const short8*)&Blds[col * 64 + (((q + 4) ^ sw) << 3)];
#pragma unroll
    for (int mt = 0; mt < 8; ++mt) {
      f32x4 acc = fzero;
      acc = __builtin_amdgcn_mfma_f32_16x16x32_bf16(afrag[mt][0], bf0, acc, 0, 0, 0);
      acc = __builtin_amdgcn_mfma_f32_16x16x32_bf16(afrag[mt][1], bf1, acc, 0, 0, 0);
#pragma unroll
      for (int rr = 0; rr < 4; ++rr) {
        lp[mt][rr] += uav * fast_tanh(qv + acc[rr]);
      }
    }
  }
  // phase E: reduce logit partials across the 16 cols held by each quarter
#pragma unroll
  for (int mt = 0; mt < 8; ++mt) {
#pragma unroll
    for (int rr = 0; rr < 4; ++rr) {
      float v = lp[mt][rr];
      v += __shfl_xor(v, 1); v += __shfl_xor(v, 2);
      v += __shfl_xor(v, 4); v += __shfl_xor(v, 8);
      lp[mt][rr] = v;
    }
  }
  if (r16 == 0) {
#pragma unroll
    for (int mt = 0; mt < 8; ++mt) {
#pragma unroll
      for (int rr = 0; rr < 4; ++rr) {
        const int n = mt * 16 + q * 4 + rr;
        float lg = lp[mt][rr];
        if (mask_lds[w][n] == 0.f) lg = -1e9f;
        logit_lds[w][n] = lg;
      }
    }
  }

  // phase F: softmax over 128 logits; write attn to out and LDS
  {
    float l0 = logit_lds[w][l], l1 = logit_lds[w][64 + l];
    float mx = fmaxf(l0, l1);
#pragma unroll
    for (int d = 1; d < 64; d <<= 1) mx = fmaxf(mx, __shfl_xor(mx, d));
    float e0 = __builtin_amdgcn_exp2f((l0 - mx) * 1.4426950408889634f);
    float e1 = __builtin_amdgcn_exp2f((l1 - mx) * 1.4426950408889634f);
    float s = e0 + e1;
#pragma unroll
    for (int d = 1; d < 64; d <<= 1) s += __shfl_xor(s, d);
    float rs = __builtin_amdgcn_rcpf(s);
    float a0 = e0 * rs, a1 = e1 * rs;
    attn_lds[w][l] = a0; attn_lds[w][64 + l] = a1;
    float* __restrict__ orow = out + (size_t)row * OUT_STRIDE;
    orow[3 + l] = a0;
    orow[3 + 64 + l] = a1;
  }

  // phase G: o_bar = sum_n attn[n] * maskedOthers[n]  (attn==0 where masked)
  {
    float ob[16];
#pragma unroll
    for (int j = 0; j < 16; ++j) ob[j] = 0.f;
#pragma unroll
    for (int mt = 0; mt < 8; ++mt) {
      const float av = attn_lds[w][mt * 16 + r16];
      const short8 f0 = afrag[mt][0], f1 = afrag[mt][1];
#pragma unroll
      for (int j = 0; j < 8; ++j) {
        ob[j] += av * bf2f(f0[j]);
        ob[8 + j] += av * bf2f(f1[j]);
      }
    }
#pragma unroll
    for (int d = 1; d < 16; d <<= 1) {
#pragma unroll
      for (int j = 0; j < 16; ++j) ob[j] += __shfl_xor(ob[j], d);
    }
    if (r16 == 0) {
#pragma unroll
      for (int j = 0; j < 8; ++j) {
        obar_lds[w][q * 8 + j] = ob[j];
        obar_lds[w][q * 8 + 32 + j] = ob[8 + j];
      }
    }
  }

  // phase H: pooled = o_bar @ W_emb + b_emb ; state = [obs[0:64], pooled] bf16
  {
    float p0 = 0.f, p1 = 0.f, p2 = 0.f, p3 = 0.f;
    for (int d = 0; d < 64; ++d) {
      float obv = obar_lds[w][d];
      short4v wv = *(const short4v*)&Wemb16[d * 256 + l * 4];
      p0 += obv * bf2f(wv[0]); p1 += obv * bf2f(wv[1]);
      p2 += obv * bf2f(wv[2]); p3 += obv * bf2f(wv[3]);
    }
    short* __restrict__ srow = state + (size_t)row * 320;
    const int j0 = l * 4;
    srow[64 + j0 + 0] = f2bf(p0 + b_emb[j0 + 0]);
    srow[64 + j0 + 1] = f2bf(p1 + b_emb[j0 + 1]);
    srow[64 + j0 + 2] = f2bf(p2 + b_emb[j0 + 2]);
    srow[64 + j0 + 3] = f2bf(p3 + b_emb[j0 + 3]);
    srow[l] = f2bf(xrow[l]);
  }
}

// ---------------- MLP GEMM: C = tanh(A @ BT^T + bias), bf16 in/out ----------------
__global__ __launch_bounds__(256) void mlp_gemm(
    const short* __restrict__ A, int lda, const short* __restrict__ BT,
    const float* __restrict__ bias, short* __restrict__ C, int ldc,
    int K, int split)
{
  __shared__ short Alds[128 * 32];
  __shared__ short Blds[128 * 32];
  const int t = threadIdx.x, l = t & 63, wid = t >> 6;
  const int bm = blockIdx.x, bn = blockIdx.y;
  const int acol0 = (split && bn >= ((int)gridDim.y >> 1)) ? K : 0;
  const int wm = wid >> 1, wn = wid & 1;
  const int q = l >> 4, r16 = l & 15;
  const f32x4 fzero = {0.f, 0.f, 0.f, 0.f};
  f32x4 acc[4][4];
#pragma unroll
  for (int fm = 0; fm < 4; ++fm)
#pragma unroll
    for (int fn = 0; fn < 4; ++fn) acc[fm][fn] = fzero;

  for (int kt = 0; kt < K; kt += 32) {
#pragma unroll
    for (int e = 0; e < 2; ++e) {
      const int ei = t + e * 256;            // [0,512)
      const int rrow = ei >> 2, c = ei & 3;
      int4 va = *(const int4*)&A[(size_t)(bm * 128 + rrow) * lda + acol0 + kt + c * 8];
      *(int4*)&Alds[rrow * 32 + ((c ^ (rrow & 3)) << 3)] = va;
      int4 vb = *(const int4*)&BT[(size_t)(bn * 128 + rrow) * K + kt + c * 8];
      *(int4*)&Blds[rrow * 32 + ((c ^ (rrow & 3)) << 3)] = vb;
    }
    __syncthreads();
    short8 af[4], bf[4];
#pragma unroll
    for (int fm = 0; fm < 4; ++fm) {
      const int ar = wm * 64 + fm * 16 + r16;
      af[fm] = *(const short8*)&Alds[ar * 32 + ((q ^ (ar & 3)) << 3)];
    }
#pragma unroll
    for (int fn = 0; fn < 4; ++fn) {
      const int br = wn * 64 + fn * 16 + r16;
      bf[fn] = *(const short8*)&Blds[br * 32 + ((q ^ (br & 3)) << 3)];
    }
#pragma unroll
    for (int fm = 0; fm < 4; ++fm)
#pragma unroll
      for (int fn = 0; fn < 4; ++fn)
        acc[fm][fn] = __builtin_amdgcn_mfma_f32_16x16x32_bf16(af[fm], bf[fn], acc[fm][fn], 0, 0, 0);
    __syncthreads();
  }

#pragma unroll
  for (int fn = 0; fn < 4; ++fn) {
    const int col = bn * 128 + wn * 64 + fn * 16 + r16;
    const float bv = bias[col];
#pragma unroll
    for (int fm = 0; fm < 4; ++fm) {
#pragma unroll
      for (int rr = 0; rr < 4; ++rr) {
        const int crow = bm * 128 + wm * 64 + fm * 16 + q * 4 + rr;
        C[(size_t)crow * ldc + col] = f2bf(fast_tanh(acc[fm][fn][rr] + bv));
      }
    }
  }
}

// ---------------- head: value + action from H2 ----------------
__global__ __launch_bounds__(256) void head_kernel(
    const short* __restrict__ H2, const float* __restrict__ W3p,
    const float* __restrict__ b3p, const float* __restrict__ W3v,
    const float* __restrict__ b3v, float* __restrict__ out)
{
  const int t = threadIdx.x, w = t >> 6, l = t & 63;
  const int row = blockIdx.x * 4 + w;
  const short* __restrict__ h = H2 + (size_t)row * 512;
  float vp0 = 0.f, vp1 = 0.f, vv = 0.f;
#pragma unroll
  for (int i = 0; i < 4; ++i) {
    const int k = i * 64 + l;
    const float hp = bf2f(h[k]);
    const float hv = bf2f(h[256 + k]);
    vp0 += hp * W3p[k * 4 + 0];
    vp1 += hp * W3p[k * 4 + 1];
    vv += hv * W3v[k];
  }
#pragma unroll
  for (int d = 1; d < 64; d <<= 1) {
    vp0 += __shfl_xor(vp0, d);
    vp1 += __shfl_xor(vp1, d);
    vv += __shfl_xor(vv, d);
  }
  if (l == 0) {
    float* __restrict__ orow = out + (size_t)row * OUT_STRIDE;
    orow[0] = vv + b3v[0];
    orow[1] = fast_tanh(vp0 + b3p[0]);
    orow[2] = fast_tanh(vp1 + b3p[1]);
  }
}

extern "C" void kernel_launch(void* const* d_in, const int* in_sizes, int n_in,
                              void* d_out, int out_size, void* d_ws, size_t ws_size,
                              hipStream_t stream) {
  (void)in_sizes; (void)n_in; (void)out_size; (void)ws_size;
  const float* inp   = (const float*)d_in[0];
  const float* W_emb = (const float*)d_in[1];
  const float* b_emb = (const float*)d_in[2];
  const float* Uq    = (const float*)d_in[3];
  const float* Ur    = (const float*)d_in[4];
  const float* Ua    = (const float*)d_in[5];
  const float* W1p   = (const float*)d_in[6];
  const float* b1p   = (const float*)d_in[7];
  const float* W2p   = (const float*)d_in[8];
  const float* b2p   = (const float*)d_in[9];
  const float* W3p   = (const float*)d_in[10];
  const float* b3p   = (const float*)d_in[11];
  const float* W1v   = (const float*)d_in[12];
  const float* b1v   = (const float*)d_in[13];
  const float* W2v   = (const float*)d_in[14];
  const float* b2v   = (const float*)d_in[15];
  const float* W3v   = (const float*)d_in[16];
  const float* b3v   = (const float*)d_in[17];

  char* ws = (char*)d_ws;
  short* WembUq  = (short*)(ws + 0);        // 64x256 bf16
  short* WembUrT = (short*)(ws + 32768);    // 256x64 bf16 (transposed)
  short* Wemb16  = (short*)(ws + 65536);    // 64x256 bf16
  float* bUq     = (float*)(ws + 98304);    // 256 f32
  float* bUr     = (float*)(ws + 99328);    // 256 f32
  float* b1cat   = (float*)(ws + 100352);   // 512 f32
  float* b2cat   = (float*)(ws + 102400);   // 512 f32
  short* W1T     = (short*)(ws + 104448);   // 512x320 bf16
  short* W2T     = (short*)(ws + 432128);   // 512x256 bf16
  short* state   = (short*)(ws + 694272);   // 4096x320 bf16
  short* H1      = (short*)(ws + 3315712);  // 4096x512 bf16
  short* H2      = (short*)(ws + 7510016);  // 4096x512 bf16

  prep_kernel<<<dim3(1282), dim3(256), 0, stream>>>(
      W_emb, b_emb, Uq, Ur, W1p, W1v, W2p, W2v, b1p, b1v, b2p, b2v,
      WembUq, WembUrT, Wemb16, bUq, bUr, b1cat, b2cat, W1T, W2T);

  attn_kernel<<<dim3(1024), dim3(256), 0, stream>>>(
      inp, WembUrT, WembUq, Wemb16, bUq, bUr, Ua, b_emb, (float*)d_out, state);

  mlp_gemm<<<dim3(32, 4), dim3(256), 0, stream>>>(state, 320, W1T, b1cat, H1, 512, 320, 0);
  mlp_gemm<<<dim3(32, 4), dim3(256), 0, stream>>>(H1, 512, W2T, b2cat, H2, 512, 256, 1);

  head_kernel<<<dim3(1024), dim3(256), 0, stream>>>(H2, W3p, b3p, W3v, b3v, (float*)d_out);
}

// Round 3
// 111.247 us; speedup vs baseline: 1.2799x; 1.2799x over previous
//
#include <hip/hip_runtime.h>

typedef __attribute__((ext_vector_type(8))) short short8;
typedef __attribute__((ext_vector_type(4))) short short4v;
typedef __attribute__((ext_vector_type(4))) float f32x4;

#define B_ROWS 4096
#define IN_STRIDE 8384
#define OUT_STRIDE 131

static __device__ __forceinline__ short f2bf(float f) {
  unsigned u = __float_as_uint(f);
  u = u + 0x7FFFu + ((u >> 16) & 1u);   // RNE
  return (short)(u >> 16);
}
static __device__ __forceinline__ float bf2f(short s) {
  return __uint_as_float(((unsigned)(unsigned short)s) << 16);
}
static __device__ __forceinline__ float fast_tanh(float x) {
  float e = __builtin_amdgcn_exp2f(x * 2.8853900817779268f);  // e^(2x)
  return 1.0f - 2.0f * __builtin_amdgcn_rcpf(e + 1.0f);
}

// ---------------- prep: fold weights, bf16 casts, transposes ----------------
__global__ __launch_bounds__(256) void prep_kernel(
    const float* __restrict__ W_emb, const float* __restrict__ b_emb,
    const float* __restrict__ Uq, const float* __restrict__ Ur,
    const float* __restrict__ W1p, const float* __restrict__ W1v,
    const float* __restrict__ W2p, const float* __restrict__ W2v,
    const float* __restrict__ b1p, const float* __restrict__ b1v,
    const float* __restrict__ b2p, const float* __restrict__ b2v,
    short* __restrict__ WembUq, short* __restrict__ WembUrT,
    short* __restrict__ Wemb16, float* __restrict__ bUq, float* __restrict__ bUr,
    float* __restrict__ b1cat, float* __restrict__ b2cat,
    short* __restrict__ W1T, short* __restrict__ W2T)
{
  const int blk = blockIdx.x, t = threadIdx.x;
  if (blk < 128) {
    const int d = blk & 63;
    const float* U = (blk < 64) ? Uq : Ur;
    float acc = 0.f;
    for (int k = 0; k < 256; ++k) acc += W_emb[d * 256 + k] * U[k * 256 + t];
    if (blk < 64) WembUq[d * 256 + t] = f2bf(acc);
    else          WembUrT[t * 64 + d] = f2bf(acc);   // [n][k] transposed
  } else if (blk == 128) {
    float aq = 0.f, ar = 0.f;
    for (int k = 0; k < 256; ++k) {
      float b = b_emb[k];
      aq += b * Uq[k * 256 + t];
      ar += b * Ur[k * 256 + t];
    }
    bUq[t] = aq; bUr[t] = ar;
  } else if (blk == 129) {
    b1cat[t] = b1p[t]; b1cat[256 + t] = b1v[t];
    b2cat[t] = b2p[t]; b2cat[256 + t] = b2v[t];
    for (int i = 0; i < 64; ++i) Wemb16[i * 256 + t] = f2bf(W_emb[i * 256 + t]);
  } else if (blk < 770) {
    const int e = (blk - 130) * 256 + t;        // [0, 163840)
    const int n = e / 320, k = e - n * 320;     // W1T[n][k], n<512, k<320
    const float v = (n < 256) ? W1p[k * 256 + n] : W1v[k * 256 + (n - 256)];
    W1T[e] = f2bf(v);
  } else {
    const int e = (blk - 770) * 256 + t;        // [0, 131072)
    const int n = e >> 8, k = e & 255;          // W2T[n][k], n<512, k<256
    const float v = (n < 256) ? W2p[k * 256 + n] : W2v[k * 256 + (n - 256)];
    W2T[e] = f2bf(v);
  }
}

// ---------------- fused attention: 1 block (4 waves) = 1 batch row ----------------
__global__ __launch_bounds__(256) void attn_kernel(
    const float* __restrict__ in, const short* __restrict__ BT,      // W_embUr^T [256][64]
    const short* __restrict__ WembUq, const short* __restrict__ Wemb16,
    const float* __restrict__ bUq, const float* __restrict__ bUr,
    const float* __restrict__ Ua, const float* __restrict__ b_emb,
    float* __restrict__ out, short* __restrict__ state)
{
  __shared__ short Blds[256 * 64];      // swizzled 16B chunks: chunk c of row n at c^(n&7)
  __shared__ float ua_lds[256];
  __shared__ float mask_lds[128];
  __shared__ float osum_p[4][64];
  __shared__ float osum_tot[64];
  __shared__ float qU_lds[256];
  __shared__ float logit_lds[128];
  __shared__ float obar_p[4][64];
  __shared__ float obar_tot[64];

  const int t = threadIdx.x, w = t >> 6, l = t & 63;
  const int q = l >> 4, r16 = l & 15;
  const int row = blockIdx.x;
  const float* __restrict__ xrow = in + (size_t)row * IN_STRIDE;
  const float* __restrict__ others = xrow + 64;
  const float* __restrict__ maskp = xrow + 8256;

  // ---- issue ALL global loads early (row data to regs, B to LDS) ----
  float m0 = maskp[l], m1 = maskp[64 + l];        // wave-redundant, L2-hit
  float4 pv[2][4];
#pragma unroll
  for (int ml = 0; ml < 2; ++ml) {
    const int gr = (2 * w + ml) * 16 + r16;
    const float4* p = (const float4*)(others + gr * 64 + q * 8);
    pv[ml][0] = p[0]; pv[ml][1] = p[1]; pv[ml][2] = p[8]; pv[ml][3] = p[9];
  }
  {
    const int4* src = (const int4*)BT;
#pragma unroll
    for (int it = 0; it < 8; ++it) {
      int cl = it * 256 + t;                 // chunk linear [0,2048)
      int n = cl >> 3, c = cl & 7;
      int4 v = src[cl];
      *(int4*)&Blds[n * 64 + ((c ^ (n & 7)) << 3)] = v;
    }
    ua_lds[t] = Ua[t];
    if (w == 0) { mask_lds[l] = m0; mask_lds[64 + l] = m1; }
  }

  // S = sum(mask), per wave from own regs
  float S = m0 + m1;
#pragma unroll
  for (int d = 1; d < 64; d <<= 1) S += __shfl_xor(S, d);

  // ---- phase B: masked bf16 A-fragments + o_sum partials (regs only) ----
  short8 afrag[2][2];
  float osA[8], osB[8];
#pragma unroll
  for (int j = 0; j < 8; ++j) { osA[j] = 0.f; osB[j] = 0.f; }
#pragma unroll
  for (int ml = 0; ml < 2; ++ml) {
    const int midx = 32 * w + 16 * ml + r16;
    const float mk = (w < 2) ? __shfl(m0, midx) : __shfl(m1, midx & 63);
    float fa[8] = {pv[ml][0].x, pv[ml][0].y, pv[ml][0].z, pv[ml][0].w,
                   pv[ml][1].x, pv[ml][1].y, pv[ml][1].z, pv[ml][1].w};
    float fb[8] = {pv[ml][2].x, pv[ml][2].y, pv[ml][2].z, pv[ml][2].w,
                   pv[ml][3].x, pv[ml][3].y, pv[ml][3].z, pv[ml][3].w};
    short8 s0, s1;
#pragma unroll
    for (int j = 0; j < 8; ++j) {
      float va = fa[j] * mk, vb = fb[j] * mk;
      osA[j] += va; osB[j] += vb;
      s0[j] = f2bf(va); s1[j] = f2bf(vb);
    }
    afrag[ml][0] = s0; afrag[ml][1] = s1;
  }
#pragma unroll
  for (int d = 1; d < 16; d <<= 1) {
#pragma unroll
    for (int j = 0; j < 8; ++j) {
      osA[j] += __shfl_xor(osA[j], d);
      osB[j] += __shfl_xor(osB[j], d);
    }
  }
  if (r16 == 0) {
#pragma unroll
    for (int j = 0; j < 8; ++j) {
      osum_p[w][q * 8 + j] = osA[j];
      osum_p[w][q * 8 + 32 + j] = osB[j];
    }
  }
  __syncthreads();

  if (t < 64) osum_tot[t] = osum_p[0][t] + osum_p[1][t] + osum_p[2][t] + osum_p[3][t];
  __syncthreads();

  // ---- phase C: qU[t] = (o_sum @ WembUq + S*bUq)/(S+1e-5) + bUr, 1 col/thread ----
  {
    float acc = 0.f;
    for (int d = 0; d < 64; ++d)
      acc += osum_tot[d] * bf2f(WembUq[d * 256 + t]);
    const float rS = __builtin_amdgcn_rcpf(S + 1e-5f);
    qU_lds[t] = (acc + S * bUq[t]) * rS + bUr[t];
  }
  __syncthreads();

  // ---- phase D: MFMA + fused tanh + Ua-dot into logit partials ----
  const f32x4 fzero = {0.f, 0.f, 0.f, 0.f};
  f32x4 lp[2];
  lp[0] = fzero; lp[1] = fzero;
  for (int nt = 0; nt < 16; ++nt) {
    const int col = nt * 16 + r16;
    const float qv = qU_lds[col];
    const float uav = ua_lds[col];
    const int sw = col & 7;
    const short8 bf0 = *(const short8*)&Blds[col * 64 + (((q) ^ sw) << 3)];
    const short8 bf1 = *(const short8*)&Blds[col * 64 + (((q + 4) ^ sw) << 3)];
#pragma unroll
    for (int ml = 0; ml < 2; ++ml) {
      f32x4 acc = fzero;
      acc = __builtin_amdgcn_mfma_f32_16x16x32_bf16(afrag[ml][0], bf0, acc, 0, 0, 0);
      acc = __builtin_amdgcn_mfma_f32_16x16x32_bf16(afrag[ml][1], bf1, acc, 0, 0, 0);
#pragma unroll
      for (int rr = 0; rr < 4; ++rr) {
        lp[ml][rr] += uav * fast_tanh(qv + acc[rr]);
      }
    }
  }
#pragma unroll
  for (int ml = 0; ml < 2; ++ml) {
#pragma unroll
    for (int rr = 0; rr < 4; ++rr) {
      float v = lp[ml][rr];
      v += __shfl_xor(v, 1); v += __shfl_xor(v, 2);
      v += __shfl_xor(v, 4); v += __shfl_xor(v, 8);
      lp[ml][rr] = v;
    }
  }
  if (r16 == 0) {
#pragma unroll
    for (int ml = 0; ml < 2; ++ml) {
#pragma unroll
      for (int rr = 0; rr < 4; ++rr) {
        const int n = (2 * w + ml) * 16 + q * 4 + rr;
        float lg = lp[ml][rr];
        if (mask_lds[n] == 0.f) lg = -1e9f;
        logit_lds[n] = lg;
      }
    }
  }
  __syncthreads();

  // ---- softmax over 128 logits (wave-redundant) ----
  float a0, a1;
  {
    float l0 = logit_lds[l], l1 = logit_lds[64 + l];
    float mx = fmaxf(l0, l1);
#pragma unroll
    for (int d = 1; d < 64; d <<= 1) mx = fmaxf(mx, __shfl_xor(mx, d));
    float e0 = __builtin_amdgcn_exp2f((l0 - mx) * 1.4426950408889634f);
    float e1 = __builtin_amdgcn_exp2f((l1 - mx) * 1.4426950408889634f);
    float s = e0 + e1;
#pragma unroll
    for (int d = 1; d < 64; d <<= 1) s += __shfl_xor(s, d);
    float rs = __builtin_amdgcn_rcpf(s);
    a0 = e0 * rs; a1 = e1 * rs;
    float* __restrict__ orow = out + (size_t)row * OUT_STRIDE;
    if (w == 0) orow[3 + l] = a0;
    if (w == 1) orow[3 + 64 + l] = a1;
  }

  // ---- phase G: o_bar partials (attn fetched via shfl, no barrier needed) ----
  {
    float ob[16];
#pragma unroll
    for (int j = 0; j < 16; ++j) ob[j] = 0.f;
#pragma unroll
    for (int ml = 0; ml < 2; ++ml) {
      const int idx = 32 * w + 16 * ml + r16;
      const float av = (w < 2) ? __shfl(a0, idx) : __shfl(a1, idx & 63);
      const short8 f0 = afrag[ml][0], f1 = afrag[ml][1];
#pragma unroll
      for (int j = 0; j < 8; ++j) {
        ob[j] += av * bf2f(f0[j]);
        ob[8 + j] += av * bf2f(f1[j]);
      }
    }
#pragma unroll
    for (int d = 1; d < 16; d <<= 1) {
#pragma unroll
      for (int j = 0; j < 16; ++j) ob[j] += __shfl_xor(ob[j], d);
    }
    if (r16 == 0) {
#pragma unroll
      for (int j = 0; j < 8; ++j) {
        obar_p[w][q * 8 + j] = ob[j];
        obar_p[w][q * 8 + 32 + j] = ob[8 + j];
      }
    }
  }
  __syncthreads();
  if (t < 64) obar_tot[t] = obar_p[0][t] + obar_p[1][t] + obar_p[2][t] + obar_p[3][t];
  __syncthreads();

  // ---- phase H: pooled col t; state = [obs[0:64], pooled] bf16 ----
  {
    float acc = 0.f;
    for (int d = 0; d < 64; ++d)
      acc += obar_tot[d] * bf2f(Wemb16[d * 256 + t]);
    short* __restrict__ srow = state + (size_t)row * 320;
    srow[64 + t] = f2bf(acc + b_emb[t]);
    if (t < 64) srow[t] = f2bf(xrow[t]);
  }
}

// ---------------- MLP GEMM: C = tanh(A @ BT^T + bias), BM=64 BN=128, bf16 ----------------
__global__ __launch_bounds__(256) void mlp_gemm(
    const short* __restrict__ A, int lda, const short* __restrict__ BT,
    const float* __restrict__ bias, short* __restrict__ C, int ldc,
    int K, int split)
{
  __shared__ short Alds[64 * 32];
  __shared__ short Blds[128 * 32];
  const int t = threadIdx.x, l = t & 63, wid = t >> 6;
  const int bm = blockIdx.x, bn = blockIdx.y;
  const int acol0 = (split && bn >= ((int)gridDim.y >> 1)) ? K : 0;
  const int wm = wid >> 1, wn = wid & 1;          // wave tile 32x64
  const int q = l >> 4, r16 = l & 15;
  const f32x4 fzero = {0.f, 0.f, 0.f, 0.f};
  f32x4 acc[2][4];
#pragma unroll
  for (int fm = 0; fm < 2; ++fm)
#pragma unroll
    for (int fn = 0; fn < 4; ++fn) acc[fm][fn] = fzero;

  for (int kt = 0; kt < K; kt += 32) {
    {
      const int rrow = t >> 2, c = t & 3;          // A: 64 rows x 4 chunks
      int4 va = *(const int4*)&A[(size_t)(bm * 64 + rrow) * lda + acol0 + kt + c * 8];
      *(int4*)&Alds[rrow * 32 + ((c ^ (rrow & 3)) << 3)] = va;
#pragma unroll
      for (int e = 0; e < 2; ++e) {
        const int ei = t + e * 256;                // B: 128 rows x 4 chunks
        const int br = ei >> 2, bc = ei & 3;
        int4 vb = *(const int4*)&BT[(size_t)(bn * 128 + br) * K + kt + bc * 8];
        *(int4*)&Blds[br * 32 + ((bc ^ (br & 3)) << 3)] = vb;
      }
    }
    __syncthreads();
    short8 af[2], bf[4];
#pragma unroll
    for (int fm = 0; fm < 2; ++fm) {
      const int ar = wm * 32 + fm * 16 + r16;
      af[fm] = *(const short8*)&Alds[ar * 32 + ((q ^ (ar & 3)) << 3)];
    }
#pragma unroll
    for (int fn = 0; fn < 4; ++fn) {
      const int br = wn * 64 + fn * 16 + r16;
      bf[fn] = *(const short8*)&Blds[br * 32 + ((q ^ (br & 3)) << 3)];
    }
#pragma unroll
    for (int fm = 0; fm < 2; ++fm)
#pragma unroll
      for (int fn = 0; fn < 4; ++fn)
        acc[fm][fn] = __builtin_amdgcn_mfma_f32_16x16x32_bf16(af[fm], bf[fn], acc[fm][fn], 0, 0, 0);
    __syncthreads();
  }

#pragma unroll
  for (int fn = 0; fn < 4; ++fn) {
    const int col = bn * 128 + wn * 64 + fn * 16 + r16;
    const float bv = bias[col];
#pragma unroll
    for (int fm = 0; fm < 2; ++fm) {
#pragma unroll
      for (int rr = 0; rr < 4; ++rr) {
        const int crow = bm * 64 + wm * 32 + fm * 16 + q * 4 + rr;
        C[(size_t)crow * ldc + col] = f2bf(fast_tanh(acc[fm][fn][rr] + bv));
      }
    }
  }
}

// ---------------- head: value + action from H2 ----------------
__global__ __launch_bounds__(256) void head_kernel(
    const short* __restrict__ H2, const float* __restrict__ W3p,
    const float* __restrict__ b3p, const float* __restrict__ W3v,
    const float* __restrict__ b3v, float* __restrict__ out)
{
  const int t = threadIdx.x, w = t >> 6, l = t & 63;
  const int row = blockIdx.x * 4 + w;
  const short* __restrict__ h = H2 + (size_t)row * 512;
  float vp0 = 0.f, vp1 = 0.f, vv = 0.f;
#pragma unroll
  for (int i = 0; i < 4; ++i) {
    const int k = i * 64 + l;
    const float hp = bf2f(h[k]);
    const float hv = bf2f(h[256 + k]);
    vp0 += hp * W3p[k * 4 + 0];
    vp1 += hp * W3p[k * 4 + 1];
    vv += hv * W3v[k];
  }
#pragma unroll
  for (int d = 1; d < 64; d <<= 1) {
    vp0 += __shfl_xor(vp0, d);
    vp1 += __shfl_xor(vp1, d);
    vv += __shfl_xor(vv, d);
  }
  if (l == 0) {
    float* __restrict__ orow = out + (size_t)row * OUT_STRIDE;
    orow[0] = vv + b3v[0];
    orow[1] = fast_tanh(vp0 + b3p[0]);
    orow[2] = fast_tanh(vp1 + b3p[1]);
  }
}

extern "C" void kernel_launch(void* const* d_in, const int* in_sizes, int n_in,
                              void* d_out, int out_size, void* d_ws, size_t ws_size,
                              hipStream_t stream) {
  (void)in_sizes; (void)n_in; (void)out_size; (void)ws_size;
  const float* inp   = (const float*)d_in[0];
  const float* W_emb = (const float*)d_in[1];
  const float* b_emb = (const float*)d_in[2];
  const float* Uq    = (const float*)d_in[3];
  const float* Ur    = (const float*)d_in[4];
  const float* Ua    = (const float*)d_in[5];
  const float* W1p   = (const float*)d_in[6];
  const float* b1p   = (const float*)d_in[7];
  const float* W2p   = (const float*)d_in[8];
  const float* b2p   = (const float*)d_in[9];
  const float* W3p   = (const float*)d_in[10];
  const float* b3p   = (const float*)d_in[11];
  const float* W1v   = (const float*)d_in[12];
  const float* b1v   = (const float*)d_in[13];
  const float* W2v   = (const float*)d_in[14];
  const float* b2v   = (const float*)d_in[15];
  const float* W3v   = (const float*)d_in[16];
  const float* b3v   = (const float*)d_in[17];

  char* ws = (char*)d_ws;
  short* WembUq  = (short*)(ws + 0);        // 64x256 bf16
  short* WembUrT = (short*)(ws + 32768);    // 256x64 bf16 (transposed)
  short* Wemb16  = (short*)(ws + 65536);    // 64x256 bf16
  float* bUq     = (float*)(ws + 98304);    // 256 f32
  float* bUr     = (float*)(ws + 99328);    // 256 f32
  float* b1cat   = (float*)(ws + 100352);   // 512 f32
  float* b2cat   = (float*)(ws + 102400);   // 512 f32
  short* W1T     = (short*)(ws + 104448);   // 512x320 bf16
  short* W2T     = (short*)(ws + 432128);   // 512x256 bf16
  short* state   = (short*)(ws + 694272);   // 4096x320 bf16
  short* H1      = (short*)(ws + 3315712);  // 4096x512 bf16
  short* H2      = (short*)(ws + 7510016);  // 4096x512 bf16

  prep_kernel<<<dim3(1282), dim3(256), 0, stream>>>(
      W_emb, b_emb, Uq, Ur, W1p, W1v, W2p, W2v, b1p, b1v, b2p, b2v,
      WembUq, WembUrT, Wemb16, bUq, bUr, b1cat, b2cat, W1T, W2T);

  attn_kernel<<<dim3(4096), dim3(256), 0, stream>>>(
      inp, WembUrT, WembUq, Wemb16, bUq, bUr, Ua, b_emb, (float*)d_out, state);

  mlp_gemm<<<dim3(64, 4), dim3(256), 0, stream>>>(state, 320, W1T, b1cat, H1, 512, 320, 0);
  mlp_gemm<<<dim3(64, 4), dim3(256), 0, stream>>>(H1, 512, W2T, b2cat, H2, 512, 256, 1);

  head_kernel<<<dim3(1024), dim3(256), 0, stream>>>(H2, W3p, b3p, W3v, b3v, (float*)d_out);
}